// Round 11
// baseline (485.073 us; speedup 1.0000x reference)
//
#include <hip/hip_runtime.h>
#include <hip/hip_bf16.h>
#include <math.h>

#define BATCH 2
#define NPT   8192
#define DIMC  128
#define NH    4
#define KNN_K 16
#define HID   32
#define BN    (BATCH*NPT)   // 16384

// ===========================================================================
// KNN via exact uniform-grid search — TAIL-FREE query (round-11 fix).
// Evidence r9/r10: dense-path cost is NOT the bottleneck (serial 44-round
// vs batched 6-round dense paths timed the same); the ~8% sparse/outlier
// queries running the r>=3 serial shell walker (200+ dependent memory
// rounds, 30+ us/wave) dominate and collapse occupancy to 13%.
// Fix: after shell 2, if the bound hasn't converged, RESET selection state
// and full-rescan all 8192 batch points (L2-resident, coalesced). Restart
// makes duplicates impossible; lex (d2,idx) selection is order-independent
// -> bit-identical to the verified r9/r10 output. r>=3 walker deleted.
// Distances: pts4 stores (2x,2y,2z,sq); d2=(qsq+sq)-dot2 bit-matches
// numpy's sq_i+sq_j-2*dot. Ties: strict lex, lowest index = lax.top_k.
// ===========================================================================
#define GRID_N 32
#define NCELL  (GRID_N*GRID_N*GRID_N)
#define GLO   -4.0f
#define GCS    0.25f
#define GINV   4.0f

__device__ __constant__ int DZ16[16] = {-2,-2,-2,-2,-2,-1,-1, 0,0, 1,1, 2,2,2,2,2};
__device__ __constant__ int DY16[16] = {-2,-1, 0, 1, 2,-2, 2,-2,2,-2,2,-2,-1,0,1,2};

__device__ __forceinline__ float readlane_f(float v, int l) {
  return __int_as_float(__builtin_amdgcn_readlane(__float_as_int(v), l));
}
__device__ __forceinline__ int clampi(int v, int lo, int hi) {
  return v < lo ? lo : (v > hi ? hi : v);
}
__device__ __forceinline__ int cell_of(float x, float y, float z) {
  const int cx = clampi((int)floorf((x - GLO)*GINV), 0, GRID_N-1);
  const int cy = clampi((int)floorf((y - GLO)*GINV), 0, GRID_N-1);
  const int cz = clampi((int)floorf((z - GLO)*GINV), 0, GRID_N-1);
  return (cz*GRID_N + cy)*GRID_N + cx;
}

__global__ __launch_bounds__(256) void zero_kernel(int* __restrict__ c) {
  const int i = blockIdx.x*256 + threadIdx.x;
  if (i < 2*NCELL) c[i] = 0;
}

__global__ __launch_bounds__(256) void count_kernel(const float* __restrict__ xyz,
                                                    int* __restrict__ counts) {
  const int i = blockIdx.x*256 + threadIdx.x;   // 0..BN-1
  const float x = xyz[(size_t)i*3+0], y = xyz[(size_t)i*3+1], z = xyz[(size_t)i*3+2];
  const int b = i >> 13;
  atomicAdd(&counts[b*NCELL + cell_of(x,y,z)], 1);
}

__global__ __launch_bounds__(1024) void scan_kernel(const int* __restrict__ counts,
                                                    int* __restrict__ starts,
                                                    int* __restrict__ cursor) {
  __shared__ int sd[1024];
  const int t = threadIdx.x;
  for (int b = 0; b < 2; ++b) {
    const int* c = counts + b*NCELL;
    int* s  = starts + b*(NCELL+1);
    int* cu = cursor + b*NCELL;
    int loc[32]; int sum = 0;
#pragma unroll
    for (int j = 0; j < 32; ++j) { loc[j] = sum; sum += c[t*32 + j]; }
    __syncthreads();           // protect sd reuse across batches
    sd[t] = sum;
    __syncthreads();
    for (int off = 1; off < 1024; off <<= 1) {
      const int u = (t >= off) ? sd[t-off] : 0;
      __syncthreads();
      sd[t] += u;
      __syncthreads();
    }
    const int excl = sd[t] - sum;
#pragma unroll
    for (int j = 0; j < 32; ++j) { s[t*32+j] = excl + loc[j]; cu[t*32+j] = excl + loc[j]; }
    if (t == 1023) s[NCELL] = sd[1023];   // = 8192
  }
}

__global__ __launch_bounds__(256) void scatter_kernel(const float* __restrict__ xyz,
    int* __restrict__ cursor, float4* __restrict__ pts4, int* __restrict__ pidx) {
  const int i = blockIdx.x*256 + threadIdx.x;
  const float x = xyz[(size_t)i*3+0], y = xyz[(size_t)i*3+1], z = xyz[(size_t)i*3+2];
  const int b = i >> 13;
  const float sq = __fadd_rn(__fadd_rn(__fmul_rn(x,x), __fmul_rn(y,y)),
                             __fmul_rn(z,z));
  const int slot = atomicAdd(&cursor[b*NCELL + cell_of(x,y,z)], 1);
  pts4[b*NPT + slot] = make_float4(x+x, y+y, z+z, sq);
  pidx[b*NPT + slot] = i & (NPT-1);   // within-batch index
}

// one wave per query; top-16 distributed over lanes 0..15, ascending lex
__global__ __launch_bounds__(256) void knn_query_kernel(const float* __restrict__ xyz,
    const int* __restrict__ starts, const float4* __restrict__ pts4,
    const int* __restrict__ pidx, int* __restrict__ knn_out) {
  const int tid = threadIdx.x, lane = tid & 63, wave = tid >> 6;
  const int p = blockIdx.x*4 + wave;
  const int b = p >> 13;
  const float qx = xyz[(size_t)p*3+0], qy = xyz[(size_t)p*3+1], qz = xyz[(size_t)p*3+2];
  const float qsq = __fadd_rn(__fadd_rn(__fmul_rn(qx,qx), __fmul_rn(qy,qy)),
                              __fmul_rn(qz,qz));
  const int cx = clampi((int)floorf((qx - GLO)*GINV), 0, GRID_N-1);
  const int cy = clampi((int)floorf((qy - GLO)*GINV), 0, GRID_N-1);
  const int cz = clampi((int)floorf((qz - GLO)*GINV), 0, GRID_N-1);
  const int*    sb = starts + b*(NCELL+1);
  const float4* pb = pts4 + (size_t)b*NPT;
  const int*    ib = pidx + (size_t)b*NPT;

  float topd = INFINITY; int topi = 0x7fffffff;
  float tau  = INFINITY; int taui = 0x7fffffff;

  auto insert_cands = [&](float d2, int di) {
    unsigned long long m = __ballot((d2 < tau) | (d2 == tau && di < taui));
    while (m) {
      const int l = (int)__builtin_ctzll(m);
      const float dn  = readlane_f(d2, l);
      const int   dni = __builtin_amdgcn_readlane(di, l);
      const float my  = topd; const int myi = topi;
      float ab  = __shfl_up(my, 1);
      int   abi = __shfl_up(myi, 1);
      if (lane == 0) { ab = -INFINITY; abi = -1; }
      const bool ge = (dn < my) | (dn == my && dni < myi);
      const bool gt = (dn < ab) | (dn == ab && dni < abi);
      topd = ge ? (gt ? ab  : dn ) : my;
      topi = ge ? (gt ? abi : dni) : myi;
      tau  = readlane_f(topd, 15);
      taui = __builtin_amdgcn_readlane(topi, 15);
      m &= (m - 1);
      if (m) m &= __ballot((d2 < tau) | (d2 == tau && di < taui));
    }
  };
  auto calc = [&](int ci, int end, float& d2, int& di) {
    d2 = INFINITY; di = 0x7fffffff;
    if (ci < end) {
      const float4 cd = pb[ci];
      const float dot2 = __fadd_rn(__fadd_rn(__fmul_rn(qx,cd.x),
                                             __fmul_rn(qy,cd.y)),
                                   __fmul_rn(qz,cd.z));
      d2 = __fsub_rn(__fadd_rn(qsq, cd.w), dot2);
      di = ib[ci];
    }
  };
  auto proc_range = [&](int beg, int end) {   // serial chunk loop
    for (int c0 = beg; c0 < end; c0 += 64) {
      float d2; int di;
      calc(c0 + lane, end, d2, di);
      insert_cands(d2, di);
    }
  };

  // ---------------- batched box r<=1 : 9 rows ----------------
  const int x0a = clampi(cx-1, 0, GRID_N-1), x1a = clampi(cx+1, 0, GRID_N-1);
  {
    int rb_[9], re_[9];
#pragma unroll
    for (int i = 0; i < 9; ++i) {
      const int z = cz + i/3 - 1, y = cy + i%3 - 1;
      const bool ok = (unsigned)z < (unsigned)GRID_N && (unsigned)y < (unsigned)GRID_N;
      const int cb = (z*GRID_N + y)*GRID_N;
      rb_[i] = ok ? __builtin_amdgcn_readfirstlane(sb[cb + x0a]) : 0;
      re_[i] = ok ? __builtin_amdgcn_readfirstlane(sb[cb + x1a + 1]) : 0;
    }
    float d2b[9]; int dib[9];
#pragma unroll
    for (int i = 0; i < 9; ++i) calc(rb_[i] + lane, re_[i], d2b[i], dib[i]);
    unsigned spill = 0;
#pragma unroll
    for (int i = 0; i < 9; ++i) {
      insert_cands(d2b[i], dib[i]);
      if (re_[i] - rb_[i] > 64) spill |= 1u << i;
    }
    while (spill) {                      // ~never taken
      const int i = __builtin_ctz(spill); spill &= spill - 1;
      const int z = cz + i/3 - 1, y = cy + i%3 - 1;
      const int cb = (z*GRID_N + y)*GRID_N;
      proc_range(sb[cb + x0a] + 64, sb[cb + x1a + 1]);
    }
  }

  const float rb1 = GCS - 1e-5f;            // bound after shells<=1
  bool need_fallback = false;
  if (!(rb1*rb1 > tau)) {
    // ---------------- batched shell r==2 ----------------
    const int x0b = clampi(cx-2, 0, GRID_N-1), x1b = clampi(cx+2, 0, GRID_N-1);
    {   // batch A: 16 full-run rows (|dz|==2 or |dy|==2)
      int rbA[16], reA[16];
#pragma unroll
      for (int i = 0; i < 16; ++i) {
        const int z = cz + DZ16[i], y = cy + DY16[i];
        const bool ok = (unsigned)z < (unsigned)GRID_N && (unsigned)y < (unsigned)GRID_N;
        const int cb = (z*GRID_N + y)*GRID_N;
        rbA[i] = ok ? __builtin_amdgcn_readfirstlane(sb[cb + x0b]) : 0;
        reA[i] = ok ? __builtin_amdgcn_readfirstlane(sb[cb + x1b + 1]) : 0;
      }
      float d2A[16]; int diA[16];
#pragma unroll
      for (int i = 0; i < 16; ++i) calc(rbA[i] + lane, reA[i], d2A[i], diA[i]);
      unsigned spill = 0;
#pragma unroll
      for (int i = 0; i < 16; ++i) {
        insert_cands(d2A[i], diA[i]);
        if (reA[i] - rbA[i] > 64) spill |= 1u << i;
      }
      while (spill) {
        const int i = __builtin_ctz(spill); spill &= spill - 1;
        const int z = cz + DZ16[i], y = cy + DY16[i];
        const int cb = (z*GRID_N + y)*GRID_N;
        proc_range(sb[cb + x0b] + 64, sb[cb + x1b + 1]);
      }
    }
    {   // batch B: 18 single-cell caps (interior rows, dx=+-2)
      int rbB[18], reB[18];
#pragma unroll
      for (int i = 0; i < 18; ++i) {
        const int row = i >> 1;
        const int z = cz + row/3 - 1, y = cy + row%3 - 1;
        const int xx = (i & 1) ? cx + 2 : cx - 2;
        const bool ok = (unsigned)z < (unsigned)GRID_N &&
                        (unsigned)y < (unsigned)GRID_N &&
                        (unsigned)xx < (unsigned)GRID_N;
        const int cb = (z*GRID_N + y)*GRID_N;
        rbB[i] = ok ? __builtin_amdgcn_readfirstlane(sb[cb + xx]) : 0;
        reB[i] = ok ? __builtin_amdgcn_readfirstlane(sb[cb + xx + 1]) : 0;
      }
      float d2B[18]; int diB[18];
#pragma unroll
      for (int i = 0; i < 18; ++i) calc(rbB[i] + lane, reB[i], d2B[i], diB[i]);
      unsigned spill = 0;
#pragma unroll
      for (int i = 0; i < 18; ++i) {
        insert_cands(d2B[i], diB[i]);
        if (reB[i] - rbB[i] > 64) spill |= 1u << i;
      }
      while (spill) {
        const int i = __builtin_ctz(spill); spill &= spill - 1;
        const int row = i >> 1;
        const int z = cz + row/3 - 1, y = cy + row%3 - 1;
        const int xx = (i & 1) ? cx + 2 : cx - 2;
        const int cb = (z*GRID_N + y)*GRID_N;
        proc_range(sb[cb + xx] + 64, sb[cb + xx + 1]);
      }
    }

    const float rb2 = 2.0f*GCS - 1e-5f;     // bound after shells<=2
    need_fallback = !(rb2*rb2 > tau);
  }

  if (need_fallback) {
    // ---- FULL RESCAN (~8% sparse queries): exact, fresh state, no dup ----
    topd = INFINITY; topi = 0x7fffffff;
    tau  = INFINITY; taui = 0x7fffffff;
    const int ntot = __builtin_amdgcn_readfirstlane(sb[NCELL]);   // = 8192
    proc_range(0, ntot);
  }

  if (lane < KNN_K) knn_out[(size_t)p*KNN_K + lane] = topi;
}

// ---------------------------------------------------------------------------
// float4-component extract (u is compile-time constant in unrolled loops)
// ---------------------------------------------------------------------------
__device__ __forceinline__ float f4c(const float4 v, int u) {
  return u == 0 ? v.x : u == 1 ? v.y : u == 2 ? v.z : v.w;
}

// ---------------------------------------------------------------------------
// Kernel 2: fused Q/K/V projection, 8-rows-per-thread register blocking.
// (unchanged)
// ---------------------------------------------------------------------------
#define QKV_ROWS 32

__global__ __launch_bounds__(128) void qkv_kernel(const float* __restrict__ x,
    const float* __restrict__ Wq, const float* __restrict__ bq,
    const float* __restrict__ Wk, const float* __restrict__ bk,
    const float* __restrict__ Wv, const float* __restrict__ bv,
    float* __restrict__ q, float* __restrict__ k, float* __restrict__ v) {
  __shared__ float xs[QKV_ROWS*DIMC];   // 16 KB
  const int tid = threadIdx.x;
  const int rowbase = blockIdx.x * QKV_ROWS;
  {
    float4* xs4 = (float4*)xs;
    const float4* src4 = (const float4*)(x + (size_t)rowbase*DIMC);
    for (int i = tid; i < QKV_ROWS*DIMC/4; i += 128) xs4[i] = src4[i];
  }
  __syncthreads();

  const int cg = tid & 31, rg = tid >> 5;   // rg 0..3
  const int c0 = cg * 4;
  float4 aq[8], ak[8], av[8];
  {
    const float4 bq4 = *(const float4*)&bq[c0];
    const float4 bk4 = *(const float4*)&bk[c0];
    const float4 bv4 = *(const float4*)&bv[c0];
#pragma unroll
    for (int i = 0; i < 8; ++i) { aq[i] = bq4; ak[i] = bk4; av[i] = bv4; }
  }

  for (int kk = 0; kk < DIMC; kk += 4) {
    float4 xr[8];
#pragma unroll
    for (int i = 0; i < 8; ++i)
      xr[i] = *(const float4*)&xs[(rg + 4*i)*DIMC + kk];
#pragma unroll
    for (int u = 0; u < 4; ++u) {
      const float4 wq = *(const float4*)&Wq[(size_t)(kk+u)*DIMC + c0];
      const float4 wk = *(const float4*)&Wk[(size_t)(kk+u)*DIMC + c0];
      const float4 wv = *(const float4*)&Wv[(size_t)(kk+u)*DIMC + c0];
#pragma unroll
      for (int i = 0; i < 8; ++i) {
        const float xv = f4c(xr[i], u);
        aq[i].x = fmaf(xv, wq.x, aq[i].x); aq[i].y = fmaf(xv, wq.y, aq[i].y);
        aq[i].z = fmaf(xv, wq.z, aq[i].z); aq[i].w = fmaf(xv, wq.w, aq[i].w);
        ak[i].x = fmaf(xv, wk.x, ak[i].x); ak[i].y = fmaf(xv, wk.y, ak[i].y);
        ak[i].z = fmaf(xv, wk.z, ak[i].z); ak[i].w = fmaf(xv, wk.w, ak[i].w);
        av[i].x = fmaf(xv, wv.x, av[i].x); av[i].y = fmaf(xv, wv.y, av[i].y);
        av[i].z = fmaf(xv, wv.z, av[i].z); av[i].w = fmaf(xv, wv.w, av[i].w);
      }
    }
  }

#pragma unroll
  for (int i = 0; i < 8; ++i) {
    const size_t rr = (size_t)(rowbase + rg + 4*i)*DIMC + c0;
    *(float4*)&q[rr] = aq[i];
    *(float4*)&k[rr] = ak[i];
    *(float4*)&v[rr] = av[i];
  }
}

// ---------------------------------------------------------------------------
// DPP ring-rotate move (VALU, no DS pipe): lane i of each 16-lane row reads
// lane (i+N)%16. Ring all-reduce with N=1,2,4,8 covers all 16 lanes.
// ---------------------------------------------------------------------------
template <int CTRL>
__device__ __forceinline__ float dppf(float x) {
  return __int_as_float(__builtin_amdgcn_update_dpp(
      __float_as_int(x), __float_as_int(x), CTRL, 0xF, 0xF, false));
}
#define ROR1 0x121
#define ROR2 0x122
#define ROR4 0x124
#define ROR8 0x128

// ---------------------------------------------------------------------------
// Kernel 3: gather + bias MLP + attention. ONE WAVE PER POINT. (unchanged)
// ---------------------------------------------------------------------------
__global__ __launch_bounds__(256) void attn_kernel(const float* __restrict__ xyz,
    const int* __restrict__ knn, const float* __restrict__ qb,
    const float* __restrict__ kb, const float* __restrict__ vb,
    const float* __restrict__ W1, const float* __restrict__ b1,
    const float* __restrict__ W2, const float* __restrict__ b2,
    float* __restrict__ ao) {
  __shared__ float sw[4][NH][KNN_K];
  __shared__ int   sn[4][KNN_K];
  const int tid  = threadIdx.x;
  const int wave = tid >> 6;
  const int lane = tid & 63;
  const int p = blockIdx.x * 4 + wave;
  const int b = p / NPT;
  const int h = lane >> 4;
  const int j = lane & 15;

  const int nj = knn[(size_t)p*KNN_K + j];
  if (h == 0) sn[wave][j] = nj;
  const size_t nn = (size_t)b*NPT + nj;

  // bias MLP for this lane's (h, j)
  const float qx0 = xyz[(size_t)p*3+0];
  const float qy0 = xyz[(size_t)p*3+1];
  const float qz0 = xyz[(size_t)p*3+2];
  const float rx = qx0 - xyz[nn*3+0];
  const float ry = qy0 - xyz[nn*3+1];
  const float rz = qz0 - xyz[nn*3+2];
  float bias = b2[h];
#pragma unroll 8
  for (int u = 0; u < HID; ++u) {
    float hv = rx*W1[0*HID+u] + ry*W1[1*HID+u] + rz*W1[2*HID+u] + b1[u];
    hv = hv > 0.f ? hv : 0.f;
    bias = fmaf(hv, W2[u*NH + h], bias);
  }

  // score: q[p,h,:] · k[nj,h,:]  (32 channels, 8x float4 each side)
  const float* qrow = qb + (size_t)p*DIMC + h*32;
  const float* krow = kb + nn*DIMC + h*32;
  float s = 0.f;
#pragma unroll
  for (int u = 0; u < 32; u += 4) {
    const float4 qv = *(const float4*)(qrow + u);
    const float4 kv = *(const float4*)(krow + u);
    s = fmaf(qv.x, kv.x, s); s = fmaf(qv.y, kv.y, s);
    s = fmaf(qv.z, kv.z, s); s = fmaf(qv.w, kv.w, s);
  }
  s = s * 0.17677669529663689f + bias;   // 1/sqrt(32)

  // softmax over the 16-lane j-group: DPP ring all-reduce (max, then sum)
  float m = s;
  m = fmaxf(m, dppf<ROR1>(m));
  m = fmaxf(m, dppf<ROR2>(m));
  m = fmaxf(m, dppf<ROR4>(m));
  m = fmaxf(m, dppf<ROR8>(m));
  const float e = expf(s - m);
  float ssum = e;
  ssum += dppf<ROR1>(ssum);
  ssum += dppf<ROR2>(ssum);
  ssum += dppf<ROR4>(ssum);
  ssum += dppf<ROR8>(ssum);
  sw[wave][h][j] = e / ssum;

  __syncthreads();

  // phase B: lane = channel d0 (and d0+64); weighted sum of v rows
  const int d0 = lane;
  const int hA = d0 >> 5;              // head of channel d0 (0 or 1)
  float out0 = 0.f, out1 = 0.f;
  const float* vbase = vb + (size_t)b*NPT*DIMC;
#pragma unroll 4
  for (int j2 = 0; j2 < KNN_K; ++j2) {
    const int n = sn[wave][j2];
    const float wA = sw[wave][hA][j2];
    const float wB = sw[wave][2+hA][j2];
    const float* vrow = vbase + (size_t)n*DIMC;
    out0 = fmaf(wA, vrow[d0],    out0);
    out1 = fmaf(wB, vrow[64+d0], out1);
  }
  ao[(size_t)p*DIMC + d0]      = out0;
  ao[(size_t)p*DIMC + 64 + d0] = out1;
}

// ---------------------------------------------------------------------------
// Kernel 4: output projection, 8-rows-per-thread register blocking,
// IN-PLACE on d_out (block stages its own 32 rows first — no hazard).
// (unchanged)
// ---------------------------------------------------------------------------
__global__ __launch_bounds__(128) void proj_kernel(float* __restrict__ inout,
    const float* __restrict__ Wo, const float* __restrict__ bo) {
  __shared__ float xs[QKV_ROWS*DIMC];   // 16 KB
  const int tid = threadIdx.x;
  const int rowbase = blockIdx.x * QKV_ROWS;
  {
    float4* xs4 = (float4*)xs;
    const float4* src4 = (const float4*)(inout + (size_t)rowbase*DIMC);
    for (int i = tid; i < QKV_ROWS*DIMC/4; i += 128) xs4[i] = src4[i];
  }
  __syncthreads();

  const int cg = tid & 31, rg = tid >> 5;   // rg 0..3
  const int c0 = cg * 4;
  float4 a[8];
  {
    const float4 bo4 = *(const float4*)&bo[c0];
#pragma unroll
    for (int i = 0; i < 8; ++i) a[i] = bo4;
  }

  for (int kk = 0; kk < DIMC; kk += 4) {
    float4 xr[8];
#pragma unroll
    for (int i = 0; i < 8; ++i)
      xr[i] = *(const float4*)&xs[(rg + 4*i)*DIMC + kk];
#pragma unroll
    for (int u = 0; u < 4; ++u) {
      const float4 w = *(const float4*)&Wo[(size_t)(kk+u)*DIMC + c0];
#pragma unroll
      for (int i = 0; i < 8; ++i) {
        const float xv = f4c(xr[i], u);
        a[i].x = fmaf(xv, w.x, a[i].x); a[i].y = fmaf(xv, w.y, a[i].y);
        a[i].z = fmaf(xv, w.z, a[i].z); a[i].w = fmaf(xv, w.w, a[i].w);
      }
    }
  }

#pragma unroll
  for (int i = 0; i < 8; ++i)
    *(float4*)&inout[(size_t)(rowbase + rg + 4*i)*DIMC + c0] = a[i];
}

// ---------------------------------------------------------------------------
extern "C" void kernel_launch(void* const* d_in, const int* in_sizes, int n_in,
                              void* d_out, int out_size, void* d_ws, size_t ws_size,
                              hipStream_t stream) {
  const float* x   = (const float*)d_in[0];
  const float* xyz = (const float*)d_in[1];
  const float* Wq  = (const float*)d_in[2];
  const float* bq  = (const float*)d_in[3];
  const float* Wk  = (const float*)d_in[4];
  const float* bk  = (const float*)d_in[5];
  const float* Wv  = (const float*)d_in[6];
  const float* bv  = (const float*)d_in[7];
  const float* Wo  = (const float*)d_in[8];
  const float* bo  = (const float*)d_in[9];
  const float* W1  = (const float*)d_in[10];
  const float* b1  = (const float*)d_in[11];
  const float* W2  = (const float*)d_in[12];
  const float* b2  = (const float*)d_in[13];
  float* out = (float*)d_out;

  // workspace layout (bytes):
  //   [0,1MB)   knn idx
  //   [1MB,9MB) q   — grid-build arrays live here transiently (dead before
  //                   qkv_kernel writes q; stream order guarantees safety)
  //   [9MB,17MB)  k
  //   [17MB,25MB) v
  char* ws = (char*)d_ws;
  int*    knn    = (int*)ws;
  char*   g      = ws + (1u<<20);
  int*    counts = (int*)g;                       // 256 KB
  int*    starts = (int*)(g + 256*1024);          // 256 KB + 8
  int*    cursor = (int*)(g + 576*1024);          // 256 KB
  float4* pts4   = (float4*)(g + 832*1024);       // 256 KB
  int*    pidx   = (int*)(g + 1088*1024);         //  64 KB
  float*  q      = (float*)(ws + (size_t)(1u<<20));
  float*  k      = (float*)(ws + (size_t)9*(1u<<20));
  float*  v      = (float*)(ws + (size_t)17*(1u<<20));

  hipLaunchKernelGGL(zero_kernel,  dim3((2*NCELL+255)/256), dim3(256), 0, stream, counts);
  hipLaunchKernelGGL(count_kernel, dim3(BN/256), dim3(256), 0, stream, xyz, counts);
  hipLaunchKernelGGL(scan_kernel,  dim3(1), dim3(1024), 0, stream, counts, starts, cursor);
  hipLaunchKernelGGL(scatter_kernel, dim3(BN/256), dim3(256), 0, stream, xyz, cursor, pts4, pidx);
  hipLaunchKernelGGL(knn_query_kernel, dim3(BN/4), dim3(256), 0, stream,
                     xyz, starts, pts4, pidx, knn);
  hipLaunchKernelGGL(qkv_kernel, dim3(BN/QKV_ROWS), dim3(128), 0, stream,
                     x, Wq, bq, Wk, bk, Wv, bv, q, k, v);
  hipLaunchKernelGGL(attn_kernel, dim3(BN/4), dim3(256), 0, stream,
                     xyz, knn, q, k, v, W1, b1, W2, b2, out);
  hipLaunchKernelGGL(proj_kernel, dim3(BN/QKV_ROWS), dim3(128), 0, stream,
                     out, Wo, bo);
}

// Round 12
// 197.796 us; speedup vs baseline: 2.4524x; 2.4524x over previous
//
#include <hip/hip_runtime.h>
#include <hip/hip_bf16.h>
#include <math.h>

#define BATCH 2
#define NPT   8192
#define DIMC  128
#define NH    4
#define KNN_K 16
#define HID   32
#define BN    (BATCH*NPT)   // 16384

// ---------------------------------------------------------------------------
// Kernel 1: exact 16-NN by squared distance — round-8 full scan (proven
// 106 µs / VALUBusy 76%) + DPP row_shr:1 insert shifts (round-12).
// The grid detour (r9-r11) lost 2.7-3.4x to latency-bound traversal and the
// Gaussian outlier tail (~18% of queries fail the shell-2 bound); reverted.
// One wave owns QPW=2 queries (2048 blocks -> 8 waves/SIMD). LDS tile
// stores (2x,2y,2z,sq): doubling is exact, so dot2 == 2*dot bit-identically
// and d2 = (qsq+sq) - dot2 matches numpy's sq_i+sq_j-2*dot rounding exactly.
// Top-16 DISTRIBUTED across lanes 0..15 (one DPP row!) sorted ascending:
// the insert shift is DPP row_shr:1 — pure VALU, no ds_permute, no lgkm
// wait; the serial per-insert chain loses both DS ops. Lanes>=16 get
// row-local garbage in topd/topi — harmless (never read: tau is
// readlane(lane 15), output writes lanes<16 only; identical situation to
// the shfl version). Ballot re-pruned after each insert. Strictly-less
// comparisons keep lower-index-wins tie order == lax.top_k.
// ---------------------------------------------------------------------------
#define TILE 1024
#define QPW  2
#define NWV  4

__device__ __forceinline__ float readlane_f(float v, int l) {
  return __int_as_float(__builtin_amdgcn_readlane(__float_as_int(v), l));
}
// DPP row_shr:1 — lane i reads lane i-1 within its 16-lane row (VALU pipe).
// Lane 0 of each row keeps its old value (bound_ctrl=false, old=src).
__device__ __forceinline__ float dpp_shr1_f(float x) {
  return __int_as_float(__builtin_amdgcn_update_dpp(
      __float_as_int(x), __float_as_int(x), 0x111, 0xF, 0xF, false));
}
__device__ __forceinline__ int dpp_shr1_i(int x) {
  return __builtin_amdgcn_update_dpp(x, x, 0x111, 0xF, 0xF, false);
}

__global__ __launch_bounds__(256) void knn_kernel(const float* __restrict__ xyz,
                                                  int* __restrict__ knn_out) {
  __shared__ float4 spts[TILE];   // 2x,2y,2z,sq per candidate (16 KB)
  const int tid  = threadIdx.x;
  const int lane = tid & 63;
  const int wave = tid >> 6;
  const int qbase = blockIdx.x * (NWV*QPW) + wave * QPW;  // flat query base
  const int b = qbase / NPT;

  float qx[QPW], qy[QPW], qz[QPW], qsq[QPW];
  float topd[QPW]; int topi[QPW]; float tau[QPW];
#pragma unroll
  for (int qi = 0; qi < QPW; ++qi) {
    const int g = qbase + qi;
    qx[qi] = xyz[(size_t)g*3+0];
    qy[qi] = xyz[(size_t)g*3+1];
    qz[qi] = xyz[(size_t)g*3+2];
    qsq[qi] = __fadd_rn(__fadd_rn(__fmul_rn(qx[qi],qx[qi]),
                                  __fmul_rn(qy[qi],qy[qi])),
                        __fmul_rn(qz[qi],qz[qi]));
    topd[qi] = 3e38f; topi[qi] = 0; tau[qi] = 3e38f;
  }

  for (int t = 0; t < NPT/TILE; ++t) {
    __syncthreads();
    // one lane = one point: 3 scalar loads, exact sq, doubled coords,
    // single ds_write_b128 (bank-conflict-free).
    const float* src = xyz + (size_t)(b*NPT + t*TILE)*3;
    for (int i = tid; i < TILE; i += 256) {
      const float x = src[i*3+0], y = src[i*3+1], z = src[i*3+2];
      const float sq = __fadd_rn(__fadd_rn(__fmul_rn(x,x), __fmul_rn(y,y)),
                                 __fmul_rn(z,z));
      spts[i] = make_float4(x+x, y+y, z+z, sq);
    }
    __syncthreads();

    for (int c = 0; c < TILE/64; ++c) {
      const float4 cd = spts[c*64 + lane];
      const int cbase = t*TILE + c*64;
#pragma unroll
      for (int qi = 0; qi < QPW; ++qi) {
        // dot2 = 2*dot, bit-exact (doubling commutes with rounding)
        float dot2 = __fadd_rn(__fadd_rn(__fmul_rn(qx[qi],cd.x),
                                         __fmul_rn(qy[qi],cd.y)),
                               __fmul_rn(qz[qi],cd.z));
        float d2 = __fsub_rn(__fadd_rn(qsq[qi], cd.w), dot2);
        unsigned long long m = __ballot(d2 < tau[qi]);
        while (m) {
          const int l = (int)__builtin_ctzll(m);
          const float dn = readlane_f(d2, l);       // SGPR broadcast, no DS
          const int   ni_ = cbase + l;
          const float my  = topd[qi];
          const int   myi = topi[qi];
          float ab  = dpp_shr1_f(my);               // VALU shift (was ds_permute)
          int   abi = dpp_shr1_i(myi);
          if (lane == 0) ab = -3e38f;
          const bool ge = dn < my;   // insert at or before this position
          const bool gt = dn < ab;   // insert strictly before -> shift down
          topd[qi] = ge ? (gt ? ab  : dn ) : my;
          topi[qi] = ge ? (gt ? abi : ni_) : myi;
          tau[qi] = readlane_f(topd[qi], 15);       // SGPR broadcast
          m &= (m - 1);
          if (m) m &= __ballot(d2 < tau[qi]);  // prune stale candidates
        }
      }
    }
  }

#pragma unroll
  for (int qi = 0; qi < QPW; ++qi) {
    if (lane < KNN_K) knn_out[(size_t)(qbase + qi)*KNN_K + lane] = topi[qi];
  }
}

// ---------------------------------------------------------------------------
// float4-component extract (u is compile-time constant in unrolled loops)
// ---------------------------------------------------------------------------
__device__ __forceinline__ float f4c(const float4 v, int u) {
  return u == 0 ? v.x : u == 1 ? v.y : u == 2 ? v.z : v.w;
}

// ---------------------------------------------------------------------------
// Kernel 2: fused Q/K/V projection, 8-rows-per-thread register blocking.
// (unchanged from round 8)
// ---------------------------------------------------------------------------
#define QKV_ROWS 32

__global__ __launch_bounds__(128) void qkv_kernel(const float* __restrict__ x,
    const float* __restrict__ Wq, const float* __restrict__ bq,
    const float* __restrict__ Wk, const float* __restrict__ bk,
    const float* __restrict__ Wv, const float* __restrict__ bv,
    float* __restrict__ q, float* __restrict__ k, float* __restrict__ v) {
  __shared__ float xs[QKV_ROWS*DIMC];   // 16 KB
  const int tid = threadIdx.x;
  const int rowbase = blockIdx.x * QKV_ROWS;
  {
    float4* xs4 = (float4*)xs;
    const float4* src4 = (const float4*)(x + (size_t)rowbase*DIMC);
    for (int i = tid; i < QKV_ROWS*DIMC/4; i += 128) xs4[i] = src4[i];
  }
  __syncthreads();

  const int cg = tid & 31, rg = tid >> 5;   // rg 0..3
  const int c0 = cg * 4;
  float4 aq[8], ak[8], av[8];
  {
    const float4 bq4 = *(const float4*)&bq[c0];
    const float4 bk4 = *(const float4*)&bk[c0];
    const float4 bv4 = *(const float4*)&bv[c0];
#pragma unroll
    for (int i = 0; i < 8; ++i) { aq[i] = bq4; ak[i] = bk4; av[i] = bv4; }
  }

  for (int kk = 0; kk < DIMC; kk += 4) {
    float4 xr[8];
#pragma unroll
    for (int i = 0; i < 8; ++i)
      xr[i] = *(const float4*)&xs[(rg + 4*i)*DIMC + kk];
#pragma unroll
    for (int u = 0; u < 4; ++u) {
      const float4 wq = *(const float4*)&Wq[(size_t)(kk+u)*DIMC + c0];
      const float4 wk = *(const float4*)&Wk[(size_t)(kk+u)*DIMC + c0];
      const float4 wv = *(const float4*)&Wv[(size_t)(kk+u)*DIMC + c0];
#pragma unroll
      for (int i = 0; i < 8; ++i) {
        const float xv = f4c(xr[i], u);
        aq[i].x = fmaf(xv, wq.x, aq[i].x); aq[i].y = fmaf(xv, wq.y, aq[i].y);
        aq[i].z = fmaf(xv, wq.z, aq[i].z); aq[i].w = fmaf(xv, wq.w, aq[i].w);
        ak[i].x = fmaf(xv, wk.x, ak[i].x); ak[i].y = fmaf(xv, wk.y, ak[i].y);
        ak[i].z = fmaf(xv, wk.z, ak[i].z); ak[i].w = fmaf(xv, wk.w, ak[i].w);
        av[i].x = fmaf(xv, wv.x, av[i].x); av[i].y = fmaf(xv, wv.y, av[i].y);
        av[i].z = fmaf(xv, wv.z, av[i].z); av[i].w = fmaf(xv, wv.w, av[i].w);
      }
    }
  }

#pragma unroll
  for (int i = 0; i < 8; ++i) {
    const size_t rr = (size_t)(rowbase + rg + 4*i)*DIMC + c0;
    *(float4*)&q[rr] = aq[i];
    *(float4*)&k[rr] = ak[i];
    *(float4*)&v[rr] = av[i];
  }
}

// ---------------------------------------------------------------------------
// DPP ring-rotate move (VALU, no DS pipe): lane i of each 16-lane row reads
// lane (i+N)%16. Ring all-reduce with N=1,2,4,8 covers all 16 lanes.
// ---------------------------------------------------------------------------
template <int CTRL>
__device__ __forceinline__ float dppf(float x) {
  return __int_as_float(__builtin_amdgcn_update_dpp(
      __float_as_int(x), __float_as_int(x), CTRL, 0xF, 0xF, false));
}
#define ROR1 0x121
#define ROR2 0x122
#define ROR4 0x124
#define ROR8 0x128

// ---------------------------------------------------------------------------
// Kernel 3: gather + bias MLP + attention. ONE WAVE PER POINT. (unchanged)
// ---------------------------------------------------------------------------
__global__ __launch_bounds__(256) void attn_kernel(const float* __restrict__ xyz,
    const int* __restrict__ knn, const float* __restrict__ qb,
    const float* __restrict__ kb, const float* __restrict__ vb,
    const float* __restrict__ W1, const float* __restrict__ b1,
    const float* __restrict__ W2, const float* __restrict__ b2,
    float* __restrict__ ao) {
  __shared__ float sw[4][NH][KNN_K];
  __shared__ int   sn[4][KNN_K];
  const int tid  = threadIdx.x;
  const int wave = tid >> 6;
  const int lane = tid & 63;
  const int p = blockIdx.x * 4 + wave;
  const int b = p / NPT;
  const int h = lane >> 4;
  const int j = lane & 15;

  const int nj = knn[(size_t)p*KNN_K + j];
  if (h == 0) sn[wave][j] = nj;
  const size_t nn = (size_t)b*NPT + nj;

  // bias MLP for this lane's (h, j)
  const float qx0 = xyz[(size_t)p*3+0];
  const float qy0 = xyz[(size_t)p*3+1];
  const float qz0 = xyz[(size_t)p*3+2];
  const float rx = qx0 - xyz[nn*3+0];
  const float ry = qy0 - xyz[nn*3+1];
  const float rz = qz0 - xyz[nn*3+2];
  float bias = b2[h];
#pragma unroll 8
  for (int u = 0; u < HID; ++u) {
    float hv = rx*W1[0*HID+u] + ry*W1[1*HID+u] + rz*W1[2*HID+u] + b1[u];
    hv = hv > 0.f ? hv : 0.f;
    bias = fmaf(hv, W2[u*NH + h], bias);
  }

  // score: q[p,h,:] · k[nj,h,:]  (32 channels, 8x float4 each side)
  const float* qrow = qb + (size_t)p*DIMC + h*32;
  const float* krow = kb + nn*DIMC + h*32;
  float s = 0.f;
#pragma unroll
  for (int u = 0; u < 32; u += 4) {
    const float4 qv = *(const float4*)(qrow + u);
    const float4 kv = *(const float4*)(krow + u);
    s = fmaf(qv.x, kv.x, s); s = fmaf(qv.y, kv.y, s);
    s = fmaf(qv.z, kv.z, s); s = fmaf(qv.w, kv.w, s);
  }
  s = s * 0.17677669529663689f + bias;   // 1/sqrt(32)

  // softmax over the 16-lane j-group: DPP ring all-reduce (max, then sum)
  float m = s;
  m = fmaxf(m, dppf<ROR1>(m));
  m = fmaxf(m, dppf<ROR2>(m));
  m = fmaxf(m, dppf<ROR4>(m));
  m = fmaxf(m, dppf<ROR8>(m));
  const float e = expf(s - m);
  float ssum = e;
  ssum += dppf<ROR1>(ssum);
  ssum += dppf<ROR2>(ssum);
  ssum += dppf<ROR4>(ssum);
  ssum += dppf<ROR8>(ssum);
  sw[wave][h][j] = e / ssum;

  __syncthreads();

  // phase B: lane = channel d0 (and d0+64); weighted sum of v rows
  const int d0 = lane;
  const int hA = d0 >> 5;              // head of channel d0 (0 or 1)
  float out0 = 0.f, out1 = 0.f;
  const float* vbase = vb + (size_t)b*NPT*DIMC;
#pragma unroll 4
  for (int j2 = 0; j2 < KNN_K; ++j2) {
    const int n = sn[wave][j2];
    const float wA = sw[wave][hA][j2];
    const float wB = sw[wave][2+hA][j2];
    const float* vrow = vbase + (size_t)n*DIMC;
    out0 = fmaf(wA, vrow[d0],    out0);
    out1 = fmaf(wB, vrow[64+d0], out1);
  }
  ao[(size_t)p*DIMC + d0]      = out0;
  ao[(size_t)p*DIMC + 64 + d0] = out1;
}

// ---------------------------------------------------------------------------
// Kernel 4: output projection, 8-rows-per-thread register blocking,
// IN-PLACE on d_out (block stages its own 32 rows first — no hazard).
// (unchanged)
// ---------------------------------------------------------------------------
__global__ __launch_bounds__(128) void proj_kernel(float* __restrict__ inout,
    const float* __restrict__ Wo, const float* __restrict__ bo) {
  __shared__ float xs[QKV_ROWS*DIMC];   // 16 KB
  const int tid = threadIdx.x;
  const int rowbase = blockIdx.x * QKV_ROWS;
  {
    float4* xs4 = (float4*)xs;
    const float4* src4 = (const float4*)(inout + (size_t)rowbase*DIMC);
    for (int i = tid; i < QKV_ROWS*DIMC/4; i += 128) xs4[i] = src4[i];
  }
  __syncthreads();

  const int cg = tid & 31, rg = tid >> 5;   // rg 0..3
  const int c0 = cg * 4;
  float4 a[8];
  {
    const float4 bo4 = *(const float4*)&bo[c0];
#pragma unroll
    for (int i = 0; i < 8; ++i) a[i] = bo4;
  }

  for (int kk = 0; kk < DIMC; kk += 4) {
    float4 xr[8];
#pragma unroll
    for (int i = 0; i < 8; ++i)
      xr[i] = *(const float4*)&xs[(rg + 4*i)*DIMC + kk];
#pragma unroll
    for (int u = 0; u < 4; ++u) {
      const float4 w = *(const float4*)&Wo[(size_t)(kk+u)*DIMC + c0];
#pragma unroll
      for (int i = 0; i < 8; ++i) {
        const float xv = f4c(xr[i], u);
        a[i].x = fmaf(xv, w.x, a[i].x); a[i].y = fmaf(xv, w.y, a[i].y);
        a[i].z = fmaf(xv, w.z, a[i].z); a[i].w = fmaf(xv, w.w, a[i].w);
      }
    }
  }

#pragma unroll
  for (int i = 0; i < 8; ++i)
    *(float4*)&inout[(size_t)(rowbase + rg + 4*i)*DIMC + c0] = a[i];
}

// ---------------------------------------------------------------------------
extern "C" void kernel_launch(void* const* d_in, const int* in_sizes, int n_in,
                              void* d_out, int out_size, void* d_ws, size_t ws_size,
                              hipStream_t stream) {
  const float* x   = (const float*)d_in[0];
  const float* xyz = (const float*)d_in[1];
  const float* Wq  = (const float*)d_in[2];
  const float* bq  = (const float*)d_in[3];
  const float* Wk  = (const float*)d_in[4];
  const float* bk  = (const float*)d_in[5];
  const float* Wv  = (const float*)d_in[6];
  const float* bv  = (const float*)d_in[7];
  const float* Wo  = (const float*)d_in[8];
  const float* bo  = (const float*)d_in[9];
  const float* W1  = (const float*)d_in[10];
  const float* b1  = (const float*)d_in[11];
  const float* W2  = (const float*)d_in[12];
  const float* b2  = (const float*)d_in[13];
  float* out = (float*)d_out;

  // workspace layout (bytes): knn idx 1MB | q 8MB | k 8MB | v 8MB  => 25MB
  char* ws = (char*)d_ws;
  int*   knn = (int*)ws;
  float* q   = (float*)(ws + (size_t)(1u<<20));
  float* k   = (float*)(ws + (size_t)9*(1u<<20));
  float* v   = (float*)(ws + (size_t)17*(1u<<20));

  hipLaunchKernelGGL(knn_kernel, dim3(BN/(NWV*QPW)), dim3(256), 0, stream, xyz, knn);
  hipLaunchKernelGGL(qkv_kernel, dim3(BN/QKV_ROWS), dim3(128), 0, stream,
                     x, Wq, bq, Wk, bk, Wv, bv, q, k, v);
  hipLaunchKernelGGL(attn_kernel, dim3(BN/4), dim3(256), 0, stream,
                     xyz, knn, q, k, v, W1, b1, W2, b2, out);
  hipLaunchKernelGGL(proj_kernel, dim3(BN/QKV_ROWS), dim3(128), 0, stream,
                     out, Wo, bo);
}

// Round 13
// 194.139 us; speedup vs baseline: 2.4986x; 1.0188x over previous
//
#include <hip/hip_runtime.h>
#include <hip/hip_bf16.h>
#include <math.h>

#define BATCH 2
#define NPT   8192
#define DIMC  128
#define NH    4
#define KNN_K 16
#define HID   32
#define BN    (BATCH*NPT)   // 16384

// ---------------------------------------------------------------------------
// Kernel 1: exact 16-NN by squared distance — round-8 full scan + DPP
// insert shifts. (unchanged from r12: 107 µs, VALUBusy 82%, issue-bound)
// ---------------------------------------------------------------------------
#define TILE 1024
#define QPW  2
#define NWV  4

__device__ __forceinline__ float readlane_f(float v, int l) {
  return __int_as_float(__builtin_amdgcn_readlane(__float_as_int(v), l));
}
// DPP row_shr:1 — lane i reads lane i-1 within its 16-lane row (VALU pipe).
__device__ __forceinline__ float dpp_shr1_f(float x) {
  return __int_as_float(__builtin_amdgcn_update_dpp(
      __float_as_int(x), __float_as_int(x), 0x111, 0xF, 0xF, false));
}
__device__ __forceinline__ int dpp_shr1_i(int x) {
  return __builtin_amdgcn_update_dpp(x, x, 0x111, 0xF, 0xF, false);
}

__global__ __launch_bounds__(256) void knn_kernel(const float* __restrict__ xyz,
                                                  int* __restrict__ knn_out) {
  __shared__ float4 spts[TILE];   // 2x,2y,2z,sq per candidate (16 KB)
  const int tid  = threadIdx.x;
  const int lane = tid & 63;
  const int wave = tid >> 6;
  const int qbase = blockIdx.x * (NWV*QPW) + wave * QPW;  // flat query base
  const int b = qbase / NPT;

  float qx[QPW], qy[QPW], qz[QPW], qsq[QPW];
  float topd[QPW]; int topi[QPW]; float tau[QPW];
#pragma unroll
  for (int qi = 0; qi < QPW; ++qi) {
    const int g = qbase + qi;
    qx[qi] = xyz[(size_t)g*3+0];
    qy[qi] = xyz[(size_t)g*3+1];
    qz[qi] = xyz[(size_t)g*3+2];
    qsq[qi] = __fadd_rn(__fadd_rn(__fmul_rn(qx[qi],qx[qi]),
                                  __fmul_rn(qy[qi],qy[qi])),
                        __fmul_rn(qz[qi],qz[qi]));
    topd[qi] = 3e38f; topi[qi] = 0; tau[qi] = 3e38f;
  }

  for (int t = 0; t < NPT/TILE; ++t) {
    __syncthreads();
    const float* src = xyz + (size_t)(b*NPT + t*TILE)*3;
    for (int i = tid; i < TILE; i += 256) {
      const float x = src[i*3+0], y = src[i*3+1], z = src[i*3+2];
      const float sq = __fadd_rn(__fadd_rn(__fmul_rn(x,x), __fmul_rn(y,y)),
                                 __fmul_rn(z,z));
      spts[i] = make_float4(x+x, y+y, z+z, sq);
    }
    __syncthreads();

    for (int c = 0; c < TILE/64; ++c) {
      const float4 cd = spts[c*64 + lane];
      const int cbase = t*TILE + c*64;
#pragma unroll
      for (int qi = 0; qi < QPW; ++qi) {
        float dot2 = __fadd_rn(__fadd_rn(__fmul_rn(qx[qi],cd.x),
                                         __fmul_rn(qy[qi],cd.y)),
                               __fmul_rn(qz[qi],cd.z));
        float d2 = __fsub_rn(__fadd_rn(qsq[qi], cd.w), dot2);
        unsigned long long m = __ballot(d2 < tau[qi]);
        while (m) {
          const int l = (int)__builtin_ctzll(m);
          const float dn = readlane_f(d2, l);
          const int   ni_ = cbase + l;
          const float my  = topd[qi];
          const int   myi = topi[qi];
          float ab  = dpp_shr1_f(my);
          int   abi = dpp_shr1_i(myi);
          if (lane == 0) ab = -3e38f;
          const bool ge = dn < my;
          const bool gt = dn < ab;
          topd[qi] = ge ? (gt ? ab  : dn ) : my;
          topi[qi] = ge ? (gt ? abi : ni_) : myi;
          tau[qi] = readlane_f(topd[qi], 15);
          m &= (m - 1);
          if (m) m &= __ballot(d2 < tau[qi]);
        }
      }
    }
  }

#pragma unroll
  for (int qi = 0; qi < QPW; ++qi) {
    if (lane < KNN_K) knn_out[(size_t)(qbase + qi)*KNN_K + lane] = topi[qi];
  }
}

// ---------------------------------------------------------------------------
// float4-component extract (u is compile-time constant in unrolled loops)
// ---------------------------------------------------------------------------
__device__ __forceinline__ float f4c(const float4 v, int u) {
  return u == 0 ? v.x : u == 1 ? v.y : u == 2 ? v.z : v.w;
}

// ---------------------------------------------------------------------------
// Kernel 2: fused Q/K/V projection, 4 rows/thread, 16 rows/block.
// r8's 8-row/32-row-block version had grid=512 -> 2 blocks/CU -> 2
// waves/SIMD: the 384 L2 W-loads/thread were latency-exposed. 4-row
// blocking doubles the grid (1024 blocks -> 4 waves/SIMD) and halves VGPR
// (48 acc) for 2x latency hiding; W traffic doubles vs r8 — measured
// irrelevant (r8: 1.5 GB saved bought only 12 µs). Each output's FMA chain
// stays kk-ascending -> bit-identical results.
// ---------------------------------------------------------------------------
#define QKV_ROWS 16

__global__ __launch_bounds__(128) void qkv_kernel(const float* __restrict__ x,
    const float* __restrict__ Wq, const float* __restrict__ bq,
    const float* __restrict__ Wk, const float* __restrict__ bk,
    const float* __restrict__ Wv, const float* __restrict__ bv,
    float* __restrict__ q, float* __restrict__ k, float* __restrict__ v) {
  __shared__ float xs[QKV_ROWS*DIMC];   // 8 KB
  const int tid = threadIdx.x;
  const int rowbase = blockIdx.x * QKV_ROWS;
  {
    float4* xs4 = (float4*)xs;
    const float4* src4 = (const float4*)(x + (size_t)rowbase*DIMC);
    for (int i = tid; i < QKV_ROWS*DIMC/4; i += 128) xs4[i] = src4[i];
  }
  __syncthreads();

  const int cg = tid & 31, rg = tid >> 5;   // rg 0..3
  const int c0 = cg * 4;
  float4 aq[4], ak[4], av[4];
  {
    const float4 bq4 = *(const float4*)&bq[c0];
    const float4 bk4 = *(const float4*)&bk[c0];
    const float4 bv4 = *(const float4*)&bv[c0];
#pragma unroll
    for (int i = 0; i < 4; ++i) { aq[i] = bq4; ak[i] = bk4; av[i] = bv4; }
  }

  for (int kk = 0; kk < DIMC; kk += 4) {
    float4 xr[4];
#pragma unroll
    for (int i = 0; i < 4; ++i)
      xr[i] = *(const float4*)&xs[(rg + 4*i)*DIMC + kk];
#pragma unroll
    for (int u = 0; u < 4; ++u) {
      const float4 wq = *(const float4*)&Wq[(size_t)(kk+u)*DIMC + c0];
      const float4 wk = *(const float4*)&Wk[(size_t)(kk+u)*DIMC + c0];
      const float4 wv = *(const float4*)&Wv[(size_t)(kk+u)*DIMC + c0];
#pragma unroll
      for (int i = 0; i < 4; ++i) {
        const float xv = f4c(xr[i], u);
        aq[i].x = fmaf(xv, wq.x, aq[i].x); aq[i].y = fmaf(xv, wq.y, aq[i].y);
        aq[i].z = fmaf(xv, wq.z, aq[i].z); aq[i].w = fmaf(xv, wq.w, aq[i].w);
        ak[i].x = fmaf(xv, wk.x, ak[i].x); ak[i].y = fmaf(xv, wk.y, ak[i].y);
        ak[i].z = fmaf(xv, wk.z, ak[i].z); ak[i].w = fmaf(xv, wk.w, ak[i].w);
        av[i].x = fmaf(xv, wv.x, av[i].x); av[i].y = fmaf(xv, wv.y, av[i].y);
        av[i].z = fmaf(xv, wv.z, av[i].z); av[i].w = fmaf(xv, wv.w, av[i].w);
      }
    }
  }

#pragma unroll
  for (int i = 0; i < 4; ++i) {
    const size_t rr = (size_t)(rowbase + rg + 4*i)*DIMC + c0;
    *(float4*)&q[rr] = aq[i];
    *(float4*)&k[rr] = ak[i];
    *(float4*)&v[rr] = av[i];
  }
}

// ---------------------------------------------------------------------------
// DPP ring-rotate move (VALU, no DS pipe): lane i of each 16-lane row reads
// lane (i+N)%16. Ring all-reduce with N=1,2,4,8 covers all 16 lanes.
// ---------------------------------------------------------------------------
template <int CTRL>
__device__ __forceinline__ float dppf(float x) {
  return __int_as_float(__builtin_amdgcn_update_dpp(
      __float_as_int(x), __float_as_int(x), CTRL, 0xF, 0xF, false));
}
#define ROR1 0x121
#define ROR2 0x122
#define ROR4 0x124
#define ROR8 0x128

// ---------------------------------------------------------------------------
// Kernel 3: gather + bias MLP + attention. ONE WAVE PER POINT. (unchanged)
// ---------------------------------------------------------------------------
__global__ __launch_bounds__(256) void attn_kernel(const float* __restrict__ xyz,
    const int* __restrict__ knn, const float* __restrict__ qb,
    const float* __restrict__ kb, const float* __restrict__ vb,
    const float* __restrict__ W1, const float* __restrict__ b1,
    const float* __restrict__ W2, const float* __restrict__ b2,
    float* __restrict__ ao) {
  __shared__ float sw[4][NH][KNN_K];
  __shared__ int   sn[4][KNN_K];
  const int tid  = threadIdx.x;
  const int wave = tid >> 6;
  const int lane = tid & 63;
  const int p = blockIdx.x * 4 + wave;
  const int b = p / NPT;
  const int h = lane >> 4;
  const int j = lane & 15;

  const int nj = knn[(size_t)p*KNN_K + j];
  if (h == 0) sn[wave][j] = nj;
  const size_t nn = (size_t)b*NPT + nj;

  // bias MLP for this lane's (h, j)
  const float qx0 = xyz[(size_t)p*3+0];
  const float qy0 = xyz[(size_t)p*3+1];
  const float qz0 = xyz[(size_t)p*3+2];
  const float rx = qx0 - xyz[nn*3+0];
  const float ry = qy0 - xyz[nn*3+1];
  const float rz = qz0 - xyz[nn*3+2];
  float bias = b2[h];
#pragma unroll 8
  for (int u = 0; u < HID; ++u) {
    float hv = rx*W1[0*HID+u] + ry*W1[1*HID+u] + rz*W1[2*HID+u] + b1[u];
    hv = hv > 0.f ? hv : 0.f;
    bias = fmaf(hv, W2[u*NH + h], bias);
  }

  // score: q[p,h,:] · k[nj,h,:]  (32 channels, 8x float4 each side)
  const float* qrow = qb + (size_t)p*DIMC + h*32;
  const float* krow = kb + nn*DIMC + h*32;
  float s = 0.f;
#pragma unroll
  for (int u = 0; u < 32; u += 4) {
    const float4 qv = *(const float4*)(qrow + u);
    const float4 kv = *(const float4*)(krow + u);
    s = fmaf(qv.x, kv.x, s); s = fmaf(qv.y, kv.y, s);
    s = fmaf(qv.z, kv.z, s); s = fmaf(qv.w, kv.w, s);
  }
  s = s * 0.17677669529663689f + bias;   // 1/sqrt(32)

  // softmax over the 16-lane j-group: DPP ring all-reduce (max, then sum)
  float m = s;
  m = fmaxf(m, dppf<ROR1>(m));
  m = fmaxf(m, dppf<ROR2>(m));
  m = fmaxf(m, dppf<ROR4>(m));
  m = fmaxf(m, dppf<ROR8>(m));
  const float e = expf(s - m);
  float ssum = e;
  ssum += dppf<ROR1>(ssum);
  ssum += dppf<ROR2>(ssum);
  ssum += dppf<ROR4>(ssum);
  ssum += dppf<ROR8>(ssum);
  sw[wave][h][j] = e / ssum;

  __syncthreads();

  // phase B: lane = channel d0 (and d0+64); weighted sum of v rows
  const int d0 = lane;
  const int hA = d0 >> 5;              // head of channel d0 (0 or 1)
  float out0 = 0.f, out1 = 0.f;
  const float* vbase = vb + (size_t)b*NPT*DIMC;
#pragma unroll 4
  for (int j2 = 0; j2 < KNN_K; ++j2) {
    const int n = sn[wave][j2];
    const float wA = sw[wave][hA][j2];
    const float wB = sw[wave][2+hA][j2];
    const float* vrow = vbase + (size_t)n*DIMC;
    out0 = fmaf(wA, vrow[d0],    out0);
    out1 = fmaf(wB, vrow[64+d0], out1);
  }
  ao[(size_t)p*DIMC + d0]      = out0;
  ao[(size_t)p*DIMC + 64 + d0] = out1;
}

// ---------------------------------------------------------------------------
// Kernel 4: output projection, 4 rows/thread, 16 rows/block (grid 1024 —
// same occupancy fix as qkv), IN-PLACE on d_out.
// ---------------------------------------------------------------------------
__global__ __launch_bounds__(128) void proj_kernel(float* __restrict__ inout,
    const float* __restrict__ Wo, const float* __restrict__ bo) {
  __shared__ float xs[QKV_ROWS*DIMC];   // 8 KB
  const int tid = threadIdx.x;
  const int rowbase = blockIdx.x * QKV_ROWS;
  {
    float4* xs4 = (float4*)xs;
    const float4* src4 = (const float4*)(inout + (size_t)rowbase*DIMC);
    for (int i = tid; i < QKV_ROWS*DIMC/4; i += 128) xs4[i] = src4[i];
  }
  __syncthreads();

  const int cg = tid & 31, rg = tid >> 5;   // rg 0..3
  const int c0 = cg * 4;
  float4 a[4];
  {
    const float4 bo4 = *(const float4*)&bo[c0];
#pragma unroll
    for (int i = 0; i < 4; ++i) a[i] = bo4;
  }

  for (int kk = 0; kk < DIMC; kk += 4) {
    float4 xr[4];
#pragma unroll
    for (int i = 0; i < 4; ++i)
      xr[i] = *(const float4*)&xs[(rg + 4*i)*DIMC + kk];
#pragma unroll
    for (int u = 0; u < 4; ++u) {
      const float4 w = *(const float4*)&Wo[(size_t)(kk+u)*DIMC + c0];
#pragma unroll
      for (int i = 0; i < 4; ++i) {
        const float xv = f4c(xr[i], u);
        a[i].x = fmaf(xv, w.x, a[i].x); a[i].y = fmaf(xv, w.y, a[i].y);
        a[i].z = fmaf(xv, w.z, a[i].z); a[i].w = fmaf(xv, w.w, a[i].w);
      }
    }
  }

#pragma unroll
  for (int i = 0; i < 4; ++i)
    *(float4*)&inout[(size_t)(rowbase + rg + 4*i)*DIMC + c0] = a[i];
}

// ---------------------------------------------------------------------------
extern "C" void kernel_launch(void* const* d_in, const int* in_sizes, int n_in,
                              void* d_out, int out_size, void* d_ws, size_t ws_size,
                              hipStream_t stream) {
  const float* x   = (const float*)d_in[0];
  const float* xyz = (const float*)d_in[1];
  const float* Wq  = (const float*)d_in[2];
  const float* bq  = (const float*)d_in[3];
  const float* Wk  = (const float*)d_in[4];
  const float* bk  = (const float*)d_in[5];
  const float* Wv  = (const float*)d_in[6];
  const float* bv  = (const float*)d_in[7];
  const float* Wo  = (const float*)d_in[8];
  const float* bo  = (const float*)d_in[9];
  const float* W1  = (const float*)d_in[10];
  const float* b1  = (const float*)d_in[11];
  const float* W2  = (const float*)d_in[12];
  const float* b2  = (const float*)d_in[13];
  float* out = (float*)d_out;

  // workspace layout (bytes): knn idx 1MB | q 8MB | k 8MB | v 8MB  => 25MB
  char* ws = (char*)d_ws;
  int*   knn = (int*)ws;
  float* q   = (float*)(ws + (size_t)(1u<<20));
  float* k   = (float*)(ws + (size_t)9*(1u<<20));
  float* v   = (float*)(ws + (size_t)17*(1u<<20));

  hipLaunchKernelGGL(knn_kernel, dim3(BN/(NWV*QPW)), dim3(256), 0, stream, xyz, knn);
  hipLaunchKernelGGL(qkv_kernel, dim3(BN/QKV_ROWS), dim3(128), 0, stream,
                     x, Wq, bq, Wk, bk, Wv, bv, q, k, v);
  hipLaunchKernelGGL(attn_kernel, dim3(BN/4), dim3(256), 0, stream,
                     xyz, knn, q, k, v, W1, b1, W2, b2, out);
  hipLaunchKernelGGL(proj_kernel, dim3(BN/QKV_ROWS), dim3(128), 0, stream,
                     out, Wo, bo);
}